// Round 14
// baseline (293.355 us; speedup 1.0000x reference)
//
#include <hip/hip_runtime.h>

// ---------------------------------------------------------------------------
// GCN + MHA + gated fuse + LayerNorm, MI355X (gfx950).
// R14: break the outproj->gate dependency algebraically:
//        gate = sigmoid(gcn@W1^T + ctx@(W2@Wo)^T + (b_g + W2@b_o))
//      Wfuse=W2@Wo computed as 36 extra blocks in the fused-gemm dispatch;
//      bias_fuse in f32 as 3 extra cast blocks. outproj + gate -> ONE merged
//      dispatch (both latency-bound at 3-4 blocks/CU; co-resident ~ max not
//      sum). scan+fill merged (LDS cursors). 9 -> 7 launches.
//      GEMM inner structure unchanged (R10 proven ceiling).
// ---------------------------------------------------------------------------

typedef __attribute__((ext_vector_type(8))) short b16x8;   // 8 bf16 = 4 VGPRs
typedef __attribute__((ext_vector_type(4))) float f32x4;

using gu32 = __attribute__((address_space(1))) const unsigned int;
using lu32 = __attribute__((address_space(3))) unsigned int;

constexpr int N  = 1024;
constexpr int B  = 8;
constexpr int D  = 768;
constexpr int H  = 8;
constexpr int DH = 96;
constexpr int E  = 16384;
constexpr int M  = N * B;          // 8192 rows, row r = n*B + b
constexpr float LN_EPS = 1e-5f;

#define DEV static __device__ __forceinline__
#define GLOAD(SRC, DST) __builtin_amdgcn_global_load_lds((gu32*)(SRC), (lu32*)(DST), 16, 0, 0)

DEV unsigned short f2b(float f) {           // f32 -> bf16 RNE
  unsigned u = __float_as_uint(f);
  u += 0x7fffu + ((u >> 16) & 1u);
  return (unsigned short)(u >> 16);
}
DEV float b2f(unsigned short h) { return __uint_as_float(((unsigned)h) << 16); }

// ---------------------------------------------------------------------------
// cast + edge-count + bias_fuse kernel.
// float4 segments: x->xb16 | gcnW->wcat | ipw->wcat+ | opw->wout & woutT(T) |
//                  gw->wg2(first half) & w2buf(second half)
// then 512 count blocks, then 3 bias_fuse blocks (f32 exact).
// ---------------------------------------------------------------------------
constexpr int CS0 = 1572864;            // x:    M*768/4
constexpr int CS1 = CS0 + 147456;       // gcnW: 768*768/4
constexpr int CS2 = CS1 + 442368;       // ipw:  2304*768/4
constexpr int CS3 = CS2 + 147456;       // opw:  768*768/4
constexpr int CS4 = CS3 + 294912;       // gw:   768*1536/4  (= 2605056)
constexpr int CAST_BLOCKS = CS4 / 256;          // 10176
constexpr int CNT_BLOCKS  = (B * E) / 256;      // 512
__global__ void cast_count_kernel(
    const float* __restrict__ x, const float* __restrict__ gcnW,
    const float* __restrict__ ipw, const float* __restrict__ opw,
    const float* __restrict__ gw, const float* __restrict__ opb,
    const float* __restrict__ gb,
    unsigned short* __restrict__ xb16, unsigned short* __restrict__ wcat,
    unsigned short* __restrict__ wout, unsigned short* __restrict__ woutT,
    unsigned short* __restrict__ wg2, unsigned short* __restrict__ w2buf,
    float* __restrict__ bias_fuse,
    const int* __restrict__ ei, int* __restrict__ cnt) {
  const int blk = blockIdx.x;
  if (blk < CAST_BLOCKS) {
    const int i = blk * 256 + threadIdx.x;
    if (i < CS0) {
      float4 v = ((const float4*)x)[i];
      ushort4 o; o.x = f2b(v.x); o.y = f2b(v.y); o.z = f2b(v.z); o.w = f2b(v.w);
      ((ushort4*)xb16)[i] = o;
    } else if (i < CS1) {
      const int off = i - CS0;
      float4 v = ((const float4*)gcnW)[off];
      ushort4 o; o.x = f2b(v.x); o.y = f2b(v.y); o.z = f2b(v.z); o.w = f2b(v.w);
      ((ushort4*)wcat)[off] = o;
    } else if (i < CS2) {
      const int off = i - CS1;
      float4 v = ((const float4*)ipw)[off];
      ushort4 o; o.x = f2b(v.x); o.y = f2b(v.y); o.z = f2b(v.z); o.w = f2b(v.w);
      ((ushort4*)(wcat + 589824))[off] = o;
    } else if (i < CS3) {
      const int off = i - CS2;
      float4 v = ((const float4*)opw)[off];
      ushort4 o; o.x = f2b(v.x); o.y = f2b(v.y); o.z = f2b(v.z); o.w = f2b(v.w);
      ((ushort4*)wout)[off] = o;
      const int e = off * 4, t = e / 768, j = e % 768;   // opw[t][j..j+3]
      woutT[(size_t)(j + 0) * 768 + t] = o.x;            // woutT[j][t]
      woutT[(size_t)(j + 1) * 768 + t] = o.y;
      woutT[(size_t)(j + 2) * 768 + t] = o.z;
      woutT[(size_t)(j + 3) * 768 + t] = o.w;
    } else {
      const int off = i - CS3;
      float4 v = ((const float4*)gw)[off];
      ushort4 o; o.x = f2b(v.x); o.y = f2b(v.y); o.z = f2b(v.z); o.w = f2b(v.w);
      const int e = off * 4, c = e / 1536, k = e % 1536;
      if (k < 768) *(ushort4*)(wg2 + (size_t)c * 1536 + k) = o;       // W1
      else         *(ushort4*)(w2buf + (size_t)c * 768 + (k - 768)) = o;  // W2
    }
  } else if (blk < CAST_BLOCKS + CNT_BLOCKS) {
    const int j = (blk - CAST_BLOCKS) * 256 + threadIdx.x;   // < B*E
    const int b = j >> 14, e = j & (E - 1);
    const int dst = ei[(b << 15) + E + e];
    atomicAdd(&cnt[(b << 10) + dst], 1);
  } else {
    // bias_fuse[c] = gb[c] + sum_t gw[c][768+t] * opb[t]   (f32, exact inputs)
    const int c = (blk - CAST_BLOCKS - CNT_BLOCKS) * 256 + threadIdx.x;  // <768
    float acc = gb[c];
    const float* wrow = gw + (size_t)c * 1536 + 768;
#pragma unroll 4
    for (int t = 0; t < 768; t += 4) {
      const float4 wv = *(const float4*)(wrow + t);
      const float4 bv = *(const float4*)(opb + t);
      acc += wv.x * bv.x + wv.y * bv.y + wv.z * bv.z + wv.w * bv.w;
    }
    bias_fuse[c] = acc;
  }
}

// per-batch scan + dinv + CSR fill (LDS cursors) in one kernel
__global__ __launch_bounds__(1024) void scan_fill_kernel(
    const int* __restrict__ cnt, int* __restrict__ offs,
    float* __restrict__ dinv, const int* __restrict__ ei,
    int* __restrict__ elist) {
  __shared__ int buf[1024];
  __shared__ int cur[1024];
  const int b = blockIdx.x, i = threadIdx.x, g = (b << 10) + i;
  const int c = cnt[g];
  buf[i] = c;
  __syncthreads();
  for (int off = 1; off < 1024; off <<= 1) {
    int t = (i >= off) ? buf[i - off] : 0;
    __syncthreads();
    buf[i] += t;
    __syncthreads();
  }
  const int excl = buf[i] - c;
  offs[g] = excl;
  dinv[g] = rsqrtf((float)(c + 1));           // self-loop included
  cur[i] = excl;
  __syncthreads();
  for (int e = i; e < E; e += 1024) {
    const int src = ei[(b << 15) + e];
    const int dst = ei[(b << 15) + E + e];
    const int slot = atomicAdd(&cur[dst], 1);
    elist[(b << 14) + slot] = src;
  }
}

// ---------------------------------------------------------------------------
// GEMM body (R10 proven structure): BM=128, BN in {64,128}, BK=32,
// double-buffered, counted vmcnt, conflict-free LDS quad swizzle.
// LDA = A row stride (for cat2 sub-panels). LDS passed in (shared by callers).
// ---------------------------------------------------------------------------
constexpr int EPI_FUSED = 0;  // c<768 -> h bf16; else qkv split
constexpr int EPI_WF    = 1;  // Wfuse -> wg2[r*1536 + 768 + c]
constexpr int EPI_OUT   = 2;  // attn_out bf16 [r*768 + c]
constexpr int EPI_GATE  = 3;  // sigmoid -> gate bf16 [r*768 + c]

template <int EPI, int BN, int K, int LDA>
DEV void gemm_body(const unsigned short* __restrict__ A,
                   const unsigned short* __restrict__ W,
                   const float* __restrict__ bias, int m0, int n0,
                   void* __restrict__ p0, void* __restrict__ p1,
                   void* __restrict__ p2, void* __restrict__ p3,
                   unsigned short* sAp, unsigned short* sBp) {
  constexpr int NW = BN / 32;
  constexpr int NT = K / 32;
  const int tid = threadIdx.x;
  const int lane = tid & 63, wid = tid >> 6;
  const int wm = wid >> 1, wn = wid & 1;
  const int l15 = lane & 15, lhi = lane >> 4;
  const int srow = lane >> 2;
  const int scol = (((lane & 3) ^ ((lane >> 3) & 3))) * 8;  // pre-swizzled src
  const int rcol = ((lhi ^ ((l15 >> 1) & 3))) * 8;          // read-side swizzle

  f32x4 acc[4][NW] = {};

  const unsigned short* pa = A + ((size_t)(m0 + wid * 32 + srow)) * LDA + scol;
  const unsigned short* pb = W + ((size_t)(n0 + wid * (BN / 4) + srow)) * K + scol;

  auto stage = [&](int buf) {
    GLOAD(pa,            sAp + (buf * 128 + wid * 32) * 32);
    GLOAD(pa + 16 * LDA, sAp + (buf * 128 + wid * 32 + 16) * 32);
    GLOAD(pb,            sBp + (buf * BN + wid * (BN / 4)) * 32);
    if constexpr (BN == 128)
      GLOAD(pb + 16 * K, sBp + (buf * BN + wid * 32 + 16) * 32);
    pa += 32; pb += 32;
  };

  stage(0);
  int cur = 0;
  for (int kt = 0; kt < NT; ++kt) {
    if (kt + 1 < NT) {
      stage(cur ^ 1);
      if constexpr (BN == 128) asm volatile("s_waitcnt vmcnt(4)" ::: "memory");
      else                     asm volatile("s_waitcnt vmcnt(3)" ::: "memory");
    } else {
      asm volatile("s_waitcnt vmcnt(0)" ::: "memory");
    }
    __builtin_amdgcn_s_barrier();
    __builtin_amdgcn_sched_barrier(0);

    b16x8 af[4], bfr[NW];
#pragma unroll
    for (int i = 0; i < 4; ++i)
      af[i] = *(const b16x8*)(sAp + (cur * 128 + wm * 64 + i * 16 + l15) * 32 + rcol);
#pragma unroll
    for (int j = 0; j < NW; ++j)
      bfr[j] = *(const b16x8*)(sBp + (cur * BN + wn * (BN / 2) + j * 16 + l15) * 32 + rcol);
#pragma unroll
    for (int i = 0; i < 4; ++i)
#pragma unroll
      for (int j = 0; j < NW; ++j)
        acc[i][j] = __builtin_amdgcn_mfma_f32_16x16x32_bf16(af[i], bfr[j], acc[i][j], 0, 0, 0);

    __builtin_amdgcn_sched_barrier(0);
    __builtin_amdgcn_s_barrier();
    cur ^= 1;
  }

  // epilogue: C/D layout col = lane&15, row = (lane>>4)*4 + reg  [HW-verified]
#pragma unroll
  for (int i = 0; i < 4; ++i) {
#pragma unroll
    for (int j = 0; j < NW; ++j) {
      const int c = n0 + wn * (BN / 2) + j * 16 + l15;
      float bv;
      if constexpr (EPI == EPI_FUSED) bv = (c < 768) ? 0.0f : bias[c - 768];
      else if constexpr (EPI == EPI_WF) bv = 0.0f;
      else bv = bias[c];
#pragma unroll
      for (int g = 0; g < 4; ++g) {
        const int r = m0 + wm * 64 + i * 16 + lhi * 4 + g;
        float v = acc[i][j][g] + bv;
        if constexpr (EPI == EPI_FUSED) {
          const int n = r >> 3, b = r & 7;
          if (c < 768) {
            ((unsigned short*)p0)[((size_t)((b << 10) + n)) * 768 + c] = f2b(v);
          } else {
            const int cc2 = c - 768;
            const int sec = cc2 / 768, cc = cc2 - sec * 768;
            const int hd = cc / 96, dh = cc - hd * 96;
            unsigned short* dst =
                (sec == 0) ? (unsigned short*)p1
                           : (sec == 1 ? (unsigned short*)p2 : (unsigned short*)p3);
            size_t idx;
            if (sec < 2) idx = ((size_t)((b * 8 + hd) * 1024 + n)) * 96 + dh;  // [B,H,N,DH]
            else         idx = ((size_t)((b * 8 + hd) * 96 + dh)) * 1024 + n;  // V^T
            dst[idx] = f2b(v);
          }
        } else if constexpr (EPI == EPI_WF) {
          ((unsigned short*)p0)[(size_t)r * 1536 + 768 + c] = f2b(v);
        } else if constexpr (EPI == EPI_OUT) {
          ((unsigned short*)p0)[(size_t)r * 768 + c] = f2b(v);
        } else {  // EPI_GATE
          ((unsigned short*)p0)[(size_t)r * 768 + c] =
              f2b(1.0f / (1.0f + __expf(-v)));
        }
      }
    }
  }
}

// fused GCN+QKV gemm (blocks [0,1536), XCD-contiguous) + Wfuse gemm (36 blocks)
__global__ __launch_bounds__(256) void gemm_fused_wf(
    const unsigned short* __restrict__ xb16, const unsigned short* __restrict__ wcat,
    const float* __restrict__ ipb,
    unsigned short* __restrict__ h16, unsigned short* __restrict__ qb,
    unsigned short* __restrict__ kb, unsigned short* __restrict__ vb,
    const unsigned short* __restrict__ w2buf, const unsigned short* __restrict__ woutT,
    unsigned short* __restrict__ wg2) {
  __shared__ __align__(16) unsigned short sAbuf[2 * 128 * 32];
  __shared__ __align__(16) unsigned short sBbuf[2 * 128 * 32];
  if (blockIdx.x < 1536) {
    const int bid = blockIdx.x;
    const int xcd = bid & 7, slot = bid >> 3;
    const int m0 = (xcd * 8 + slot / 24) * 128, n0 = (slot % 24) * 128;
    gemm_body<EPI_FUSED, 128, 768, 768>(xb16, wcat, ipb, m0, n0,
                                        h16, qb, kb, vb, sAbuf, sBbuf);
  } else {
    const int b2 = blockIdx.x - 1536;           // 6x6 over 768x768
    const int m0 = (b2 / 6) * 128, n0 = (b2 % 6) * 128;
    gemm_body<EPI_WF, 128, 768, 768>(w2buf, woutT, nullptr, m0, n0,
                                     wg2, nullptr, nullptr, nullptr, sAbuf, sBbuf);
  }
}

// merged out-proj (blocks [0,768)) + gate (blocks [768,1536)) — independent
// after the Wfuse rewrite; both latency-bound -> co-residency ~ max not sum.
__global__ __launch_bounds__(256) void gemm_op_gate(
    const unsigned short* __restrict__ cat2, const unsigned short* __restrict__ wout,
    const float* __restrict__ opb, unsigned short* __restrict__ attnf16,
    const unsigned short* __restrict__ wg2, const float* __restrict__ bias_fuse,
    unsigned short* __restrict__ gate16) {
  __shared__ __align__(16) unsigned short sAbuf[2 * 128 * 32];
  __shared__ __align__(16) unsigned short sBbuf[2 * 64 * 32];
  if (blockIdx.x < 768) {
    const int bid = blockIdx.x;
    const int xcd = bid & 7, slot = bid >> 3;
    const int m0 = (xcd * 8 + slot / 12) * 128, n0 = (slot % 12) * 64;
    gemm_body<EPI_OUT, 64, 768, 1536>(cat2 + 768, wout, opb, m0, n0,
                                      attnf16, nullptr, nullptr, nullptr, sAbuf, sBbuf);
  } else {
    const int bid = blockIdx.x - 768;
    const int xcd = bid & 7, slot = bid >> 3;
    const int m0 = (xcd * 8 + slot / 12) * 128, n0 = (slot % 12) * 64;
    gemm_body<EPI_GATE, 64, 1536, 1536>(cat2, wg2, bias_fuse, m0, n0,
                                        gate16, nullptr, nullptr, nullptr, sAbuf, sBbuf);
  }
}

// ---------------------------------------------------------------------------
// MERGED attention + GCN aggregation (R13 structure; ctx -> cat2[:,768:]).
// ---------------------------------------------------------------------------
__global__ __launch_bounds__(256) void attn_agg_kernel(
    const unsigned short* __restrict__ qb, const unsigned short* __restrict__ kb,
    const unsigned short* __restrict__ vb, unsigned short* __restrict__ cat2,
    const unsigned short* __restrict__ h16,
    const int* __restrict__ cnt, const int* __restrict__ offs,
    const int* __restrict__ elist, const float* __restrict__ dinv,
    const float* __restrict__ gcn_b) {
  __shared__ __align__(16) unsigned short sK[64][104];  // [key][dh], pad 96->104
  __shared__ __align__(16) unsigned short sV[96][72];   // [dh][key], pad 64->72
  __shared__ __align__(16) unsigned short sP[4][16][72];

  if (blockIdx.x >= 1024) {
    // ===================== aggregation path =====================
    if (threadIdx.x >= 192) return;     // 192 thr x 4 dims = 768
    const int abid = blockIdx.x - 1024;
    const int b = abid & 7, n = abid >> 3;   // batch -> XCD
    const int bn = (b << 10) + n;
    const int d = threadIdx.x * 4;
    const float dn = dinv[bn];
    const size_t hrow = (size_t)bn * 768;
    ushort4 hv = *(const ushort4*)(h16 + hrow + d);
    float a0 = dn * dn * b2f(hv.x), a1 = dn * dn * b2f(hv.y);
    float a2 = dn * dn * b2f(hv.z), a3 = dn * dn * b2f(hv.w);
    const int st = offs[bn], cv = cnt[bn];
    const int* ep = elist + (b << 14) + st;
    int i = 0;
    for (; i + 2 <= cv; i += 2) {
      const int s0 = ep[i], s1 = ep[i + 1];
      const float nv0 = dinv[(b << 10) + s0] * dn;
      const float nv1 = dinv[(b << 10) + s1] * dn;
      const ushort4 r0 = *(const ushort4*)(h16 + ((size_t)((b << 10) + s0)) * 768 + d);
      const ushort4 r1 = *(const ushort4*)(h16 + ((size_t)((b << 10) + s1)) * 768 + d);
      a0 += nv0 * b2f(r0.x) + nv1 * b2f(r1.x);
      a1 += nv0 * b2f(r0.y) + nv1 * b2f(r1.y);
      a2 += nv0 * b2f(r0.z) + nv1 * b2f(r1.z);
      a3 += nv0 * b2f(r0.w) + nv1 * b2f(r1.w);
    }
    if (i < cv) {
      const int s0 = ep[i];
      const float nv0 = dinv[(b << 10) + s0] * dn;
      const ushort4 r0 = *(const ushort4*)(h16 + ((size_t)((b << 10) + s0)) * 768 + d);
      a0 += nv0 * b2f(r0.x); a1 += nv0 * b2f(r0.y);
      a2 += nv0 * b2f(r0.z); a3 += nv0 * b2f(r0.w);
    }
    const float4 bb = *(const float4*)(gcn_b + d);
    a0 += bb.x; a1 += bb.y; a2 += bb.z; a3 += bb.w;
    const size_t crow = ((size_t)n * 8 + b) * 1536;
    ushort4 co; co.x = f2b(a0); co.y = f2b(a1); co.z = f2b(a2); co.w = f2b(a3);
    *(ushort4*)(cat2 + crow + d) = co;
    return;
  }

  // ===================== attention path =====================
  const int tid = threadIdx.x, lane = tid & 63, wid = tid >> 6;
  const int l15 = lane & 15, lhi = lane >> 4;
  const int bid = blockIdx.x;
  const int xcd = bid & 7, slot = bid >> 3;
  const int bh = xcd * 8 + (slot >> 4);
  const int q0 = (slot & 15) * 64;
  const float SCL = 0.14724445f;  // (1/sqrt(96)) * log2(e)

  b16x8 qf[3];
  const size_t qbase = ((size_t)bh * 1024 + q0 + wid * 16 + l15) * 96 + lhi * 8;
#pragma unroll
  for (int ks = 0; ks < 3; ++ks) qf[ks] = *(const b16x8*)(qb + qbase + ks * 32);

  const int c0 = tid, c1 = 256 + tid, c2 = 512 + tid;
  const unsigned short* kp0 = kb + ((size_t)bh * 1024 + c0 / 12) * 96 + (c0 % 12) * 8;
  const unsigned short* kp1 = kb + ((size_t)bh * 1024 + c1 / 12) * 96 + (c1 % 12) * 8;
  const unsigned short* kp2 = kb + ((size_t)bh * 1024 + c2 / 12) * 96 + (c2 % 12) * 8;
  const unsigned short* vp0 = vb + ((size_t)bh * 96 + (c0 >> 3)) * 1024 + (c0 & 7) * 8;
  const unsigned short* vp1 = vb + ((size_t)bh * 96 + (c1 >> 3)) * 1024 + (c1 & 7) * 8;
  const unsigned short* vp2 = vb + ((size_t)bh * 96 + (c2 >> 3)) * 1024 + (c2 & 7) * 8;
  unsigned short* sk0 = &sK[c0 / 12][(c0 % 12) * 8];
  unsigned short* sk1 = &sK[c1 / 12][(c1 % 12) * 8];
  unsigned short* sk2 = &sK[c2 / 12][(c2 % 12) * 8];
  unsigned short* sv0 = &sV[c0 >> 3][(c0 & 7) * 8];
  unsigned short* sv1 = &sV[c1 >> 3][(c1 & 7) * 8];
  unsigned short* sv2 = &sV[c2 >> 3][(c2 & 7) * 8];

  uint4 k0 = *(const uint4*)kp0, k1 = *(const uint4*)kp1, k2 = *(const uint4*)kp2;
  uint4 v0 = *(const uint4*)vp0, v1 = *(const uint4*)vp1, v2 = *(const uint4*)vp2;

  f32x4 accO[6] = {};
  float ssum[4] = {0.f, 0.f, 0.f, 0.f};

  for (int kt = 0; kt < 16; ++kt) {
    __syncthreads();
    *(uint4*)sk0 = k0; *(uint4*)sk1 = k1; *(uint4*)sk2 = k2;
    *(uint4*)sv0 = v0; *(uint4*)sv1 = v1; *(uint4*)sv2 = v2;
    __syncthreads();
    if (kt < 15) {
      kp0 += 64 * 96; kp1 += 64 * 96; kp2 += 64 * 96;
      vp0 += 64;      vp1 += 64;      vp2 += 64;
      k0 = *(const uint4*)kp0; k1 = *(const uint4*)kp1; k2 = *(const uint4*)kp2;
      v0 = *(const uint4*)vp0; v1 = *(const uint4*)vp1; v2 = *(const uint4*)vp2;
    }

    f32x4 sf[4] = {};
    __builtin_amdgcn_s_setprio(1);
#pragma unroll
    for (int f = 0; f < 4; ++f) {
#pragma unroll
      for (int ks = 0; ks < 3; ++ks) {
        b16x8 kf = *(const b16x8*)&sK[f * 16 + l15][ks * 32 + lhi * 8];
        sf[f] = __builtin_amdgcn_mfma_f32_16x16x32_bf16(qf[ks], kf, sf[f], 0, 0, 0);
      }
    }
    __builtin_amdgcn_s_setprio(0);

#pragma unroll
    for (int g = 0; g < 4; ++g) {
#pragma unroll
      for (int f = 0; f < 4; ++f) {
        const float pv = exp2f(sf[f][g] * SCL);
        sP[wid][lhi * 4 + g][f * 16 + l15] = f2b(pv);
        ssum[g] += pv;
      }
    }

    __builtin_amdgcn_s_setprio(1);
#pragma unroll
    for (int ks = 0; ks < 2; ++ks) {
      b16x8 pa = *(const b16x8*)&sP[wid][l15][ks * 32 + lhi * 8];
#pragma unroll
      for (int o = 0; o < 6; ++o) {
        b16x8 vf = *(const b16x8*)&sV[o * 16 + l15][ks * 32 + lhi * 8];
        accO[o] = __builtin_amdgcn_mfma_f32_16x16x32_bf16(pa, vf, accO[o], 0, 0, 0);
      }
    }
    __builtin_amdgcn_s_setprio(0);
  }

#pragma unroll
  for (int g = 0; g < 4; ++g) {
#pragma unroll
    for (int msk = 1; msk < 16; msk <<= 1) ssum[g] += __shfl_xor(ssum[g], msk);
  }

  const int b = bh >> 3, hd = bh & 7;
  float rinv[4];
#pragma unroll
  for (int g = 0; g < 4; ++g) rinv[g] = 1.0f / ssum[g];
#pragma unroll
  for (int o = 0; o < 6; ++o)
#pragma unroll
    for (int g = 0; g < 4; ++g) {
      const int qrow = q0 + wid * 16 + lhi * 4 + g;
      cat2[((size_t)qrow * 8 + b) * 1536 + 768 + hd * 96 + o * 16 + l15] =
          f2b(accO[o][g] * rinv[g]);
    }
}

// ---------------------------------------------------------------------------
// gate-blend + residual + LayerNorm. block (192 thr) per row.
// gcn from cat2[:, :768]; attn from attnf16; gate from gate16; x f32 residual.
// ---------------------------------------------------------------------------
__global__ __launch_bounds__(192) void ln_fuse_kernel(
    const unsigned short* __restrict__ gate16,
    const unsigned short* __restrict__ cat2,
    const unsigned short* __restrict__ attnf16,
    const float* __restrict__ x,
    const float* __restrict__ lng, const float* __restrict__ lnb,
    float* __restrict__ out) {
  const int r = blockIdx.x;
  const int t = threadIdx.x, lane = t & 63, wid = t >> 6;   // 3 waves
  const int d = t * 4;
  const size_t xrow = (size_t)r * 768;
  const size_t crow = (size_t)r * 1536;
  const ushort4 gv = *(const ushort4*)(gate16 + xrow + d);
  const ushort4 cv = *(const ushort4*)(cat2 + crow + d);      // gcn
  const ushort4 av = *(const ushort4*)(attnf16 + xrow + d);   // attn_out
  const float4 xv = *(const float4*)(x + xrow + d);
  const float g0 = b2f(gv.x), g1 = b2f(gv.y), g2 = b2f(gv.z), g3 = b2f(gv.w);
  float f0 = g0 * b2f(cv.x) + (1.f - g0) * b2f(av.x) + xv.x;
  float f1 = g1 * b2f(cv.y) + (1.f - g1) * b2f(av.y) + xv.y;
  float f2 = g2 * b2f(cv.z) + (1.f - g2) * b2f(av.z) + xv.z;
  float f3 = g3 * b2f(cv.w) + (1.f - g3) * b2f(av.w) + xv.w;
  float s1 = f0 + f1 + f2 + f3;
  float s2 = f0 * f0 + f1 * f1 + f2 * f2 + f3 * f3;
#pragma unroll
  for (int msk = 1; msk < 64; msk <<= 1) {
    s1 += __shfl_xor(s1, msk);
    s2 += __shfl_xor(s2, msk);
  }
  __shared__ float p1[3], p2[3];
  if (lane == 0) { p1[wid] = s1; p2[wid] = s2; }
  __syncthreads();
  s1 = p1[0] + p1[1] + p1[2];
  s2 = p2[0] + p2[1] + p2[2];
  const float mu = s1 * (1.f / 768.f);
  float var = s2 * (1.f / 768.f) - mu * mu;
  var = fmaxf(var, 0.f);
  const float rstd = rsqrtf(var + LN_EPS);
  const float4 lg = *(const float4*)(lng + d);
  const float4 lb = *(const float4*)(lnb + d);
  float4 o;
  o.x = (f0 - mu) * rstd * lg.x + lb.x;
  o.y = (f1 - mu) * rstd * lg.y + lb.y;
  o.z = (f2 - mu) * rstd * lg.z + lb.z;
  o.w = (f3 - mu) * rstd * lg.w + lb.w;
  *(float4*)(out + xrow + d) = o;
}

// ---------------------------------------------------------------------------
extern "C" void kernel_launch(void* const* d_in, const int* in_sizes, int n_in,
                              void* d_out, int out_size, void* d_ws, size_t ws_size,
                              hipStream_t stream) {
  const float* x     = (const float*)d_in[0];
  const int*   ei    = (const int*)d_in[1];
  const float* gcnW  = (const float*)d_in[2];
  const float* gcnb  = (const float*)d_in[3];
  const float* ipw   = (const float*)d_in[4];
  const float* ipb   = (const float*)d_in[5];
  const float* opw   = (const float*)d_in[6];
  const float* opb   = (const float*)d_in[7];
  const float* gw    = (const float*)d_in[8];
  const float* gb    = (const float*)d_in[9];
  const float* lng   = (const float*)d_in[10];
  const float* lnb   = (const float*)d_in[11];
  float* out = (float*)d_out;

  char* p = (char*)d_ws;
  auto alloc = [&](size_t bytes) { void* q = p; p += (bytes + 255) & ~(size_t)255; return q; };

  unsigned short* xb16  = (unsigned short*)alloc((size_t)M * 768 * 2);
  unsigned short* wcat  = (unsigned short*)alloc((size_t)3072 * 768 * 2); // [wgcn;wqkv]
  unsigned short* wout  = (unsigned short*)alloc((size_t)768 * 768 * 2);
  unsigned short* woutT = (unsigned short*)alloc((size_t)768 * 768 * 2);
  unsigned short* w2buf = (unsigned short*)alloc((size_t)768 * 768 * 2);
  unsigned short* wg2   = (unsigned short*)alloc((size_t)768 * 1536 * 2); // [W1|Wfuse]
  unsigned short* qb    = (unsigned short*)alloc((size_t)B * H * N * DH * 2); // also gate16
  unsigned short* kb    = (unsigned short*)alloc((size_t)B * H * N * DH * 2); // also attnf16
  unsigned short* vb    = (unsigned short*)alloc((size_t)B * H * DH * N * 2);
  unsigned short* h16   = (unsigned short*)alloc((size_t)M * 768 * 2);
  unsigned short* cat2  = (unsigned short*)alloc((size_t)M * 1536 * 2);   // [gcn|ctx]
  float* bias_fuse      = (float*)alloc(768 * 4);
  int* cnt    = (int*)alloc(8192 * 4);
  int* offs   = (int*)alloc(8192 * 4);
  float* dinv = (float*)alloc(8192 * 4);
  int* elist  = (int*)alloc((size_t)B * E * 4);

  // safe aliases (serial-stream ordering makes these race-free):
  unsigned short* gate16  = qb;   // written by op_gate AFTER attn reads qb
  unsigned short* attnf16 = kb;   // written by op_gate AFTER attn reads kb

  // 1) zero degree counters; casts + edge_count + bias_fuse in one launch
  hipMemsetAsync(cnt, 0, 8192 * 4, stream);
  cast_count_kernel<<<CAST_BLOCKS + CNT_BLOCKS + 3, 256, 0, stream>>>(
      x, gcnW, ipw, opw, gw, opb, gb,
      xb16, wcat, wout, woutT, wg2, w2buf, bias_fuse, ei, cnt);

  // 2) CSR scan + fill (one kernel, LDS cursors)
  scan_fill_kernel<<<8, 1024, 0, stream>>>(cnt, offs, dinv, ei, elist);

  // 3) fused GCN+QKV gemm (+Wfuse gemm riding along); attn+agg; outproj||gate
  gemm_fused_wf<<<1536 + 36, 256, 0, stream>>>(
      xb16, wcat, ipb, h16, qb, kb, vb, w2buf, woutT, wg2);
  attn_agg_kernel<<<1024 + 8192, 256, 0, stream>>>(
      qb, kb, vb, cat2, h16, cnt, offs, elist, dinv, gcnb);
  gemm_op_gate<<<1536, 256, 0, stream>>>(
      cat2, wout, opb, attnf16, wg2, bias_fuse, gate16);

  // 4) gate blend + residual + LayerNorm
  ln_fuse_kernel<<<8192, 192, 0, stream>>>(gate16, cat2, attnf16, x, lng, lnb, out);
}

// Round 15
// 266.019 us; speedup vs baseline: 1.1028x; 1.1028x over previous
//
#include <hip/hip_runtime.h>

// ---------------------------------------------------------------------------
// GCN + MHA + gated fuse + LayerNorm, MI355X (gfx950).
// R15: revert to R13 (best known 256.4us). R14's Wfuse algebra regressed:
//      scattered woutT transpose writes + 36 tail blocks on fused gemm +
//      op_gate merge that didn't co-schedule as max. Keep only R14's safe
//      piece: merged scan+fill CSR kernel (8 launches total).
//      All GEMMs pinned at ~440TF = measured 2-phase-128^2 structure ceiling
//      for K in {768,1536} (6 structural variants falsified). LN at HBM
//      roofline; cast near memory floor.
// ---------------------------------------------------------------------------

typedef __attribute__((ext_vector_type(8))) short b16x8;   // 8 bf16 = 4 VGPRs
typedef __attribute__((ext_vector_type(4))) float f32x4;

using gu32 = __attribute__((address_space(1))) const unsigned int;
using lu32 = __attribute__((address_space(3))) unsigned int;

constexpr int N  = 1024;
constexpr int B  = 8;
constexpr int D  = 768;
constexpr int H  = 8;
constexpr int DH = 96;
constexpr int E  = 16384;
constexpr int M  = N * B;          // 8192 rows, row r = n*B + b
constexpr float LN_EPS = 1e-5f;

#define DEV static __device__ __forceinline__
#define GLOAD(SRC, DST) __builtin_amdgcn_global_load_lds((gu32*)(SRC), (lu32*)(DST), 16, 0, 0)

DEV unsigned short f2b(float f) {           // f32 -> bf16 RNE
  unsigned u = __float_as_uint(f);
  u += 0x7fffu + ((u >> 16) & 1u);
  return (unsigned short)(u >> 16);
}
DEV float b2f(unsigned short h) { return __uint_as_float(((unsigned)h) << 16); }

// ---------------------------------------------------------------------------
// merged cast (5 f32->bf16 segments) + edge_count kernel.
// ---------------------------------------------------------------------------
constexpr int CS0 = 1572864;            // x:    M*768/4
constexpr int CS1 = CS0 + 147456;       // gcnW: 768*768/4
constexpr int CS2 = CS1 + 442368;       // ipw:  2304*768/4
constexpr int CS3 = CS2 + 147456;       // opw:  768*768/4
constexpr int CS4 = CS3 + 294912;       // gw:   768*1536/4  (= 2605056)
constexpr int CAST_BLOCKS = CS4 / 256;          // 10176
constexpr int CNT_BLOCKS  = (B * E) / 256;      // 512
__global__ void cast_count_kernel(
    const float* __restrict__ x, const float* __restrict__ gcnW,
    const float* __restrict__ ipw, const float* __restrict__ opw,
    const float* __restrict__ gw,
    unsigned short* __restrict__ xb16, unsigned short* __restrict__ wcat,
    unsigned short* __restrict__ wout, unsigned short* __restrict__ wgate,
    const int* __restrict__ ei, int* __restrict__ cnt) {
  const int blk = blockIdx.x;
  if (blk < CAST_BLOCKS) {
    const int i = blk * 256 + threadIdx.x;
    const float* in; unsigned short* out; int off;
    if (i < CS0)      { in = x;    out = xb16;           off = i; }
    else if (i < CS1) { in = gcnW; out = wcat;           off = i - CS0; }
    else if (i < CS2) { in = ipw;  out = wcat + 589824;  off = i - CS1; }
    else if (i < CS3) { in = opw;  out = wout;           off = i - CS2; }
    else              { in = gw;   out = wgate;          off = i - CS3; }
    float4 v = ((const float4*)in)[off];
    ushort4 o;
    o.x = f2b(v.x); o.y = f2b(v.y); o.z = f2b(v.z); o.w = f2b(v.w);
    ((ushort4*)out)[off] = o;
  } else {
    const int j = (blk - CAST_BLOCKS) * 256 + threadIdx.x;   // < B*E
    const int b = j >> 14, e = j & (E - 1);
    const int dst = ei[(b << 15) + E + e];
    atomicAdd(&cnt[(b << 10) + dst], 1);
  }
}

// per-batch scan + dinv + CSR fill (LDS cursors) in one kernel
__global__ __launch_bounds__(1024) void scan_fill_kernel(
    const int* __restrict__ cnt, int* __restrict__ offs,
    float* __restrict__ dinv, const int* __restrict__ ei,
    int* __restrict__ elist) {
  __shared__ int buf[1024];
  __shared__ int cur[1024];
  const int b = blockIdx.x, i = threadIdx.x, g = (b << 10) + i;
  const int c = cnt[g];
  buf[i] = c;
  __syncthreads();
  for (int off = 1; off < 1024; off <<= 1) {
    int t = (i >= off) ? buf[i - off] : 0;
    __syncthreads();
    buf[i] += t;
    __syncthreads();
  }
  const int excl = buf[i] - c;
  offs[g] = excl;
  dinv[g] = rsqrtf((float)(c + 1));           // self-loop included
  cur[i] = excl;
  __syncthreads();
  for (int e = i; e < E; e += 1024) {
    const int src = ei[(b << 15) + e];
    const int dst = ei[(b << 15) + E + e];
    const int slot = atomicAdd(&cur[dst], 1);
    elist[(b << 14) + slot] = src;
  }
}

// ---------------------------------------------------------------------------
// bf16 MFMA GEMM (R10 structure — proven ceiling for this shape):
// BM=128, BN in {64,128}, BK=32, double-buffered, counted vmcnt,
// conflict-free LDS quad swizzle, XCD-contiguous grid.
// ---------------------------------------------------------------------------
constexpr int EPI_FUSED = 0;  // c<768 -> h bf16 [B,N,D]; else qkv split
constexpr int EPI_ATTN  = 1;  // -> cat bf16 [r, 768+c]
constexpr int EPI_GATE  = 2;  // -> sigmoid -> gate bf16 [r,c]

template <int EPI, int BN, int K, int GX, int GY>
__global__ __launch_bounds__(256) void gemm_bt(
    const unsigned short* __restrict__ A, const unsigned short* __restrict__ W,
    const float* __restrict__ bias,
    void* __restrict__ p0, void* __restrict__ p1, void* __restrict__ p2,
    void* __restrict__ p3) {
  constexpr int NW = BN / 32;          // n-fragments per wave
  constexpr int NT = K / 32;           // K-steps
  __shared__ __align__(16) unsigned short sA[2][128][32];
  __shared__ __align__(16) unsigned short sB[2][BN][32];
  const int tid = threadIdx.x;
  const int lane = tid & 63, wid = tid >> 6;
  const int wm = wid >> 1, wn = wid & 1;
  const int bid = blockIdx.x;
  const int xcd = bid & 7, slot = bid >> 3;
  const int by = xcd * (GY / 8) + slot / GX;
  const int bx = slot % GX;
  const int m0 = by * 128, n0 = bx * BN;
  const int l15 = lane & 15, lhi = lane >> 4;
  const int srow = lane >> 2;
  const int scol = (((lane & 3) ^ ((lane >> 3) & 3))) * 8;  // pre-swizzled src
  const int rcol = ((lhi ^ ((l15 >> 1) & 3))) * 8;          // read-side swizzle

  f32x4 acc[4][NW] = {};

  const unsigned short* pa = A + ((size_t)(m0 + wid * 32 + srow)) * K + scol;
  const unsigned short* pb = W + ((size_t)(n0 + wid * (BN / 4) + srow)) * K + scol;

  auto stage = [&](int buf) {
    GLOAD(pa,          &sA[buf][wid * 32][0]);
    GLOAD(pa + 16 * K, &sA[buf][wid * 32 + 16][0]);
    GLOAD(pb,          &sB[buf][wid * (BN / 4)][0]);
    if constexpr (BN == 128) GLOAD(pb + 16 * K, &sB[buf][wid * 32 + 16][0]);
    pa += 32; pb += 32;
  };

  stage(0);
  int cur = 0;
  for (int kt = 0; kt < NT; ++kt) {
    if (kt + 1 < NT) {
      stage(cur ^ 1);
      if constexpr (BN == 128) asm volatile("s_waitcnt vmcnt(4)" ::: "memory");
      else                     asm volatile("s_waitcnt vmcnt(3)" ::: "memory");
    } else {
      asm volatile("s_waitcnt vmcnt(0)" ::: "memory");
    }
    __builtin_amdgcn_s_barrier();
    __builtin_amdgcn_sched_barrier(0);

    b16x8 af[4], bfr[NW];
#pragma unroll
    for (int i = 0; i < 4; ++i)
      af[i] = *(const b16x8*)&sA[cur][wm * 64 + i * 16 + l15][rcol];
#pragma unroll
    for (int j = 0; j < NW; ++j)
      bfr[j] = *(const b16x8*)&sB[cur][wn * (BN / 2) + j * 16 + l15][rcol];
#pragma unroll
    for (int i = 0; i < 4; ++i)
#pragma unroll
      for (int j = 0; j < NW; ++j)
        acc[i][j] = __builtin_amdgcn_mfma_f32_16x16x32_bf16(af[i], bfr[j], acc[i][j], 0, 0, 0);

    __builtin_amdgcn_sched_barrier(0);
    __builtin_amdgcn_s_barrier();
    cur ^= 1;
  }

  // epilogue: C/D layout col = lane&15, row = (lane>>4)*4 + reg  [HW-verified]
#pragma unroll
  for (int i = 0; i < 4; ++i) {
#pragma unroll
    for (int j = 0; j < NW; ++j) {
      const int c = n0 + wn * (BN / 2) + j * 16 + l15;
      float bv;
      if constexpr (EPI == EPI_FUSED) bv = (c < 768) ? 0.0f : bias[c - 768];
      else bv = bias[c];
#pragma unroll
      for (int g = 0; g < 4; ++g) {
        const int r = m0 + wm * 64 + i * 16 + lhi * 4 + g;
        float v = acc[i][j][g] + bv;
        if constexpr (EPI == EPI_FUSED) {
          const int n = r >> 3, b = r & 7;
          if (c < 768) {
            ((unsigned short*)p0)[((size_t)((b << 10) + n)) * 768 + c] = f2b(v);
          } else {
            const int cc2 = c - 768;
            const int sec = cc2 / 768, cc = cc2 - sec * 768;
            const int hd = cc / 96, dh = cc - hd * 96;
            unsigned short* dst =
                (sec == 0) ? (unsigned short*)p1
                           : (sec == 1 ? (unsigned short*)p2 : (unsigned short*)p3);
            size_t idx;
            if (sec < 2) idx = ((size_t)((b * 8 + hd) * 1024 + n)) * 96 + dh;  // [B,H,N,DH]
            else         idx = ((size_t)((b * 8 + hd) * 96 + dh)) * 1024 + n;  // V^T
            dst[idx] = f2b(v);
          }
        } else if constexpr (EPI == EPI_ATTN) {
          ((unsigned short*)p0)[(size_t)r * 1536 + 768 + c] = f2b(v);
        } else {  // EPI_GATE -> bf16 gate
          ((unsigned short*)p0)[(size_t)r * 768 + c] =
              f2b(1.0f / (1.0f + __expf(-v)));
        }
      }
    }
  }
}

// ---------------------------------------------------------------------------
// MERGED attention + GCN aggregation (data-independent, complementary pipes).
// blocks [0,1024): flash attention (XCD-grouped by bid&7).
// blocks [1024,9216): aggregation, batch->XCD mapping b = abid&7.
// ---------------------------------------------------------------------------
__global__ __launch_bounds__(256) void attn_agg_kernel(
    const unsigned short* __restrict__ qb, const unsigned short* __restrict__ kb,
    const unsigned short* __restrict__ vb, unsigned short* __restrict__ ctx,
    const unsigned short* __restrict__ h16,
    const int* __restrict__ cnt, const int* __restrict__ offs,
    const int* __restrict__ elist, const float* __restrict__ dinv,
    const float* __restrict__ gcn_b, unsigned short* __restrict__ cat16) {
  __shared__ __align__(16) unsigned short sK[64][104];  // [key][dh], pad 96->104
  __shared__ __align__(16) unsigned short sV[96][72];   // [dh][key], pad 64->72
  __shared__ __align__(16) unsigned short sP[4][16][72];

  if (blockIdx.x >= 1024) {
    // ===================== aggregation path =====================
    if (threadIdx.x >= 192) return;     // 192 thr x 4 dims = 768
    const int abid = blockIdx.x - 1024;
    const int b = abid & 7, n = abid >> 3;   // batch -> XCD
    const int bn = (b << 10) + n;
    const int d = threadIdx.x * 4;
    const float dn = dinv[bn];
    const size_t hrow = (size_t)bn * 768;
    ushort4 hv = *(const ushort4*)(h16 + hrow + d);
    float a0 = dn * dn * b2f(hv.x), a1 = dn * dn * b2f(hv.y);
    float a2 = dn * dn * b2f(hv.z), a3 = dn * dn * b2f(hv.w);
    const int st = offs[bn], cv = cnt[bn];
    const int* ep = elist + (b << 14) + st;
    int i = 0;
    for (; i + 2 <= cv; i += 2) {       // two independent gathers in flight
      const int s0 = ep[i], s1 = ep[i + 1];
      const float nv0 = dinv[(b << 10) + s0] * dn;
      const float nv1 = dinv[(b << 10) + s1] * dn;
      const ushort4 r0 = *(const ushort4*)(h16 + ((size_t)((b << 10) + s0)) * 768 + d);
      const ushort4 r1 = *(const ushort4*)(h16 + ((size_t)((b << 10) + s1)) * 768 + d);
      a0 += nv0 * b2f(r0.x) + nv1 * b2f(r1.x);
      a1 += nv0 * b2f(r0.y) + nv1 * b2f(r1.y);
      a2 += nv0 * b2f(r0.z) + nv1 * b2f(r1.z);
      a3 += nv0 * b2f(r0.w) + nv1 * b2f(r1.w);
    }
    if (i < cv) {
      const int s0 = ep[i];
      const float nv0 = dinv[(b << 10) + s0] * dn;
      const ushort4 r0 = *(const ushort4*)(h16 + ((size_t)((b << 10) + s0)) * 768 + d);
      a0 += nv0 * b2f(r0.x); a1 += nv0 * b2f(r0.y);
      a2 += nv0 * b2f(r0.z); a3 += nv0 * b2f(r0.w);
    }
    const float4 bb = *(const float4*)(gcn_b + d);
    a0 += bb.x; a1 += bb.y; a2 += bb.z; a3 += bb.w;
    const size_t crow = ((size_t)n * 8 + b) * 1536;
    ushort4 co; co.x = f2b(a0); co.y = f2b(a1); co.z = f2b(a2); co.w = f2b(a3);
    *(ushort4*)(cat16 + crow + d) = co;
    return;
  }

  // ===================== attention path =====================
  const int tid = threadIdx.x, lane = tid & 63, wid = tid >> 6;
  const int l15 = lane & 15, lhi = lane >> 4;
  const int bid = blockIdx.x;
  const int xcd = bid & 7, slot = bid >> 3;
  const int bh = xcd * 8 + (slot >> 4);
  const int q0 = (slot & 15) * 64;
  const float SCL = 0.14724445f;  // (1/sqrt(96)) * log2(e)

  b16x8 qf[3];
  const size_t qbase = ((size_t)bh * 1024 + q0 + wid * 16 + l15) * 96 + lhi * 8;
#pragma unroll
  for (int ks = 0; ks < 3; ++ks) qf[ks] = *(const b16x8*)(qb + qbase + ks * 32);

  const int c0 = tid, c1 = 256 + tid, c2 = 512 + tid;
  const unsigned short* kp0 = kb + ((size_t)bh * 1024 + c0 / 12) * 96 + (c0 % 12) * 8;
  const unsigned short* kp1 = kb + ((size_t)bh * 1024 + c1 / 12) * 96 + (c1 % 12) * 8;
  const unsigned short* kp2 = kb + ((size_t)bh * 1024 + c2 / 12) * 96 + (c2 % 12) * 8;
  const unsigned short* vp0 = vb + ((size_t)bh * 96 + (c0 >> 3)) * 1024 + (c0 & 7) * 8;
  const unsigned short* vp1 = vb + ((size_t)bh * 96 + (c1 >> 3)) * 1024 + (c1 & 7) * 8;
  const unsigned short* vp2 = vb + ((size_t)bh * 96 + (c2 >> 3)) * 1024 + (c2 & 7) * 8;
  unsigned short* sk0 = &sK[c0 / 12][(c0 % 12) * 8];
  unsigned short* sk1 = &sK[c1 / 12][(c1 % 12) * 8];
  unsigned short* sk2 = &sK[c2 / 12][(c2 % 12) * 8];
  unsigned short* sv0 = &sV[c0 >> 3][(c0 & 7) * 8];
  unsigned short* sv1 = &sV[c1 >> 3][(c1 & 7) * 8];
  unsigned short* sv2 = &sV[c2 >> 3][(c2 & 7) * 8];

  uint4 k0 = *(const uint4*)kp0, k1 = *(const uint4*)kp1, k2 = *(const uint4*)kp2;
  uint4 v0 = *(const uint4*)vp0, v1 = *(const uint4*)vp1, v2 = *(const uint4*)vp2;

  f32x4 accO[6] = {};
  float ssum[4] = {0.f, 0.f, 0.f, 0.f};

  for (int kt = 0; kt < 16; ++kt) {
    __syncthreads();
    *(uint4*)sk0 = k0; *(uint4*)sk1 = k1; *(uint4*)sk2 = k2;
    *(uint4*)sv0 = v0; *(uint4*)sv1 = v1; *(uint4*)sv2 = v2;
    __syncthreads();
    if (kt < 15) {
      kp0 += 64 * 96; kp1 += 64 * 96; kp2 += 64 * 96;
      vp0 += 64;      vp1 += 64;      vp2 += 64;
      k0 = *(const uint4*)kp0; k1 = *(const uint4*)kp1; k2 = *(const uint4*)kp2;
      v0 = *(const uint4*)vp0; v1 = *(const uint4*)vp1; v2 = *(const uint4*)vp2;
    }

    f32x4 sf[4] = {};
    __builtin_amdgcn_s_setprio(1);
#pragma unroll
    for (int f = 0; f < 4; ++f) {
#pragma unroll
      for (int ks = 0; ks < 3; ++ks) {
        b16x8 kf = *(const b16x8*)&sK[f * 16 + l15][ks * 32 + lhi * 8];
        sf[f] = __builtin_amdgcn_mfma_f32_16x16x32_bf16(qf[ks], kf, sf[f], 0, 0, 0);
      }
    }
    __builtin_amdgcn_s_setprio(0);

#pragma unroll
    for (int g = 0; g < 4; ++g) {
#pragma unroll
      for (int f = 0; f < 4; ++f) {
        const float pv = exp2f(sf[f][g] * SCL);
        sP[wid][lhi * 4 + g][f * 16 + l15] = f2b(pv);
        ssum[g] += pv;
      }
    }

    __builtin_amdgcn_s_setprio(1);
#pragma unroll
    for (int ks = 0; ks < 2; ++ks) {
      b16x8 pa = *(const b16x8*)&sP[wid][l15][ks * 32 + lhi * 8];
#pragma unroll
      for (int o = 0; o < 6; ++o) {
        b16x8 vf = *(const b16x8*)&sV[o * 16 + l15][ks * 32 + lhi * 8];
        accO[o] = __builtin_amdgcn_mfma_f32_16x16x32_bf16(pa, vf, accO[o], 0, 0, 0);
      }
    }
    __builtin_amdgcn_s_setprio(0);
  }

#pragma unroll
  for (int g = 0; g < 4; ++g) {
#pragma unroll
    for (int msk = 1; msk < 16; msk <<= 1) ssum[g] += __shfl_xor(ssum[g], msk);
  }

  const int b = bh >> 3, hd = bh & 7;
  float rinv[4];
#pragma unroll
  for (int g = 0; g < 4; ++g) rinv[g] = 1.0f / ssum[g];
#pragma unroll
  for (int o = 0; o < 6; ++o)
#pragma unroll
    for (int g = 0; g < 4; ++g) {
      const int qrow = q0 + wid * 16 + lhi * 4 + g;
      ctx[((size_t)qrow * 8 + b) * 768 + hd * 96 + o * 16 + l15] =
          f2b(accO[o][g] * rinv[g]);
    }
}

// ---------------------------------------------------------------------------
// gate-blend + residual + LayerNorm. block (192 thr) per row.
// ---------------------------------------------------------------------------
__global__ __launch_bounds__(192) void ln_fuse_kernel(
    const unsigned short* __restrict__ gate16,
    const unsigned short* __restrict__ cat16,
    const float* __restrict__ x,
    const float* __restrict__ lng, const float* __restrict__ lnb,
    float* __restrict__ out) {
  const int r = blockIdx.x;
  const int t = threadIdx.x, lane = t & 63, wid = t >> 6;   // 3 waves
  const int d = t * 4;
  const size_t xrow = (size_t)r * 768;
  const size_t crow = (size_t)r * 1536;
  const ushort4 gv = *(const ushort4*)(gate16 + xrow + d);
  const ushort4 cv = *(const ushort4*)(cat16 + crow + d);        // gcn
  const ushort4 av = *(const ushort4*)(cat16 + crow + 768 + d);  // attn
  const float4 xv = *(const float4*)(x + xrow + d);
  const float g0 = b2f(gv.x), g1 = b2f(gv.y), g2 = b2f(gv.z), g3 = b2f(gv.w);
  float f0 = g0 * b2f(cv.x) + (1.f - g0) * b2f(av.x) + xv.x;
  float f1 = g1 * b2f(cv.y) + (1.f - g1) * b2f(av.y) + xv.y;
  float f2 = g2 * b2f(cv.z) + (1.f - g2) * b2f(av.z) + xv.z;
  float f3 = g3 * b2f(cv.w) + (1.f - g3) * b2f(av.w) + xv.w;
  float s1 = f0 + f1 + f2 + f3;
  float s2 = f0 * f0 + f1 * f1 + f2 * f2 + f3 * f3;
#pragma unroll
  for (int msk = 1; msk < 64; msk <<= 1) {
    s1 += __shfl_xor(s1, msk);
    s2 += __shfl_xor(s2, msk);
  }
  __shared__ float p1[3], p2[3];
  if (lane == 0) { p1[wid] = s1; p2[wid] = s2; }
  __syncthreads();
  s1 = p1[0] + p1[1] + p1[2];
  s2 = p2[0] + p2[1] + p2[2];
  const float mu = s1 * (1.f / 768.f);
  float var = s2 * (1.f / 768.f) - mu * mu;
  var = fmaxf(var, 0.f);
  const float rstd = rsqrtf(var + LN_EPS);
  const float4 lg = *(const float4*)(lng + d);
  const float4 lb = *(const float4*)(lnb + d);
  float4 o;
  o.x = (f0 - mu) * rstd * lg.x + lb.x;
  o.y = (f1 - mu) * rstd * lg.y + lb.y;
  o.z = (f2 - mu) * rstd * lg.z + lb.z;
  o.w = (f3 - mu) * rstd * lg.w + lb.w;
  *(float4*)(out + xrow + d) = o;
}

// ---------------------------------------------------------------------------
extern "C" void kernel_launch(void* const* d_in, const int* in_sizes, int n_in,
                              void* d_out, int out_size, void* d_ws, size_t ws_size,
                              hipStream_t stream) {
  const float* x     = (const float*)d_in[0];
  const int*   ei    = (const int*)d_in[1];
  const float* gcnW  = (const float*)d_in[2];
  const float* gcnb  = (const float*)d_in[3];
  const float* ipw   = (const float*)d_in[4];
  const float* ipb   = (const float*)d_in[5];
  const float* opw   = (const float*)d_in[6];
  const float* opb   = (const float*)d_in[7];
  const float* gw    = (const float*)d_in[8];
  const float* gb    = (const float*)d_in[9];
  const float* lng   = (const float*)d_in[10];
  const float* lnb   = (const float*)d_in[11];
  float* out = (float*)d_out;

  char* p = (char*)d_ws;
  auto alloc = [&](size_t bytes) { void* q = p; p += (bytes + 255) & ~(size_t)255; return q; };

  unsigned short* xb16  = (unsigned short*)alloc((size_t)M * 768 * 2);   // also ctx16
  unsigned short* wcat  = (unsigned short*)alloc((size_t)3072 * 768 * 2); // [wgcn;wqkv]
  unsigned short* wout  = (unsigned short*)alloc((size_t)768 * 768 * 2);
  unsigned short* wgate = (unsigned short*)alloc((size_t)768 * 1536 * 2);
  unsigned short* qb    = (unsigned short*)alloc((size_t)B * H * N * DH * 2); // also gate16
  unsigned short* kb    = (unsigned short*)alloc((size_t)B * H * N * DH * 2);
  unsigned short* vb    = (unsigned short*)alloc((size_t)B * H * DH * N * 2);
  unsigned short* h16   = (unsigned short*)alloc((size_t)M * 768 * 2);
  unsigned short* cat16 = (unsigned short*)alloc((size_t)M * 1536 * 2);
  int* cnt    = (int*)alloc(8192 * 4);
  int* offs   = (int*)alloc(8192 * 4);
  float* dinv = (float*)alloc(8192 * 4);
  int* elist  = (int*)alloc((size_t)B * E * 4);

  // safe aliases (serial-stream ordering makes these race-free):
  unsigned short* ctx16  = xb16;  // written by attn AFTER last read of xb16 (fused gemm)
  unsigned short* gate16 = qb;    // written by gate gemm AFTER attn reads qb

  // 1) zero degree counters (stream-ordered), then casts + edge_count
  hipMemsetAsync(cnt, 0, 8192 * 4, stream);
  cast_count_kernel<<<CAST_BLOCKS + CNT_BLOCKS, 256, 0, stream>>>(
      x, gcnW, ipw, opw, gw, xb16, wcat, wout, wgate, ei, cnt);

  // 2) CSR scan + fill (one kernel, LDS cursors)
  scan_fill_kernel<<<8, 1024, 0, stream>>>(cnt, offs, dinv, ei, elist);

  // 3) fused GCN-linear + QKV GEMM; merged attn+agg; out-proj; gate
  gemm_bt<EPI_FUSED, 128, 768, 24, 64><<<1536, 256, 0, stream>>>(
      xb16, wcat, ipb, (void*)h16, (void*)qb, (void*)kb, (void*)vb);
  attn_agg_kernel<<<1024 + 8192, 256, 0, stream>>>(
      qb, kb, vb, ctx16, h16, cnt, offs, elist, dinv, gcnb, cat16);
  gemm_bt<EPI_ATTN, 64, 768, 12, 64><<<768, 256, 0, stream>>>(
      ctx16, wout, opb, (void*)cat16, nullptr, nullptr, nullptr);
  gemm_bt<EPI_GATE, 64, 1536, 12, 64><<<768, 256, 0, stream>>>(
      cat16, wgate, gb, (void*)gate16, nullptr, nullptr, nullptr);

  // 4) gate blend + residual + LayerNorm
  ln_fuse_kernel<<<8192, 192, 0, stream>>>(gate16, cat16, x, lng, lnb, out);
}

// Round 16
// 256.870 us; speedup vs baseline: 1.1420x; 1.0356x over previous
//
#include <hip/hip_runtime.h>

// ---------------------------------------------------------------------------
// GCN + MHA + gated fuse + LayerNorm, MI355X (gfx950).
// R16: exact revert to R13 (best measured 256.4us). R15's merged scan_fill
//      serialized the CSR fill onto 8 CUs (LDS-cursor atomics, 16 strides)
//      vs R13's 512-block global-atomic fill -> ~12us regression. Restore
//      separate scan_offs + edge_fill.
//      State of play: GEMMs at 2-phase 128^2 structure ceiling (~440TF,
//      6 escalations falsified; 8-phase 256^2 spills acc twice); attn+agg
//      merged; LN at HBM roofline; cast near memory floor.
// ---------------------------------------------------------------------------

typedef __attribute__((ext_vector_type(8))) short b16x8;   // 8 bf16 = 4 VGPRs
typedef __attribute__((ext_vector_type(4))) float f32x4;

using gu32 = __attribute__((address_space(1))) const unsigned int;
using lu32 = __attribute__((address_space(3))) unsigned int;

constexpr int N  = 1024;
constexpr int B  = 8;
constexpr int D  = 768;
constexpr int H  = 8;
constexpr int DH = 96;
constexpr int E  = 16384;
constexpr int M  = N * B;          // 8192 rows, row r = n*B + b
constexpr float LN_EPS = 1e-5f;

#define DEV static __device__ __forceinline__
#define GLOAD(SRC, DST) __builtin_amdgcn_global_load_lds((gu32*)(SRC), (lu32*)(DST), 16, 0, 0)

DEV unsigned short f2b(float f) {           // f32 -> bf16 RNE
  unsigned u = __float_as_uint(f);
  u += 0x7fffu + ((u >> 16) & 1u);
  return (unsigned short)(u >> 16);
}
DEV float b2f(unsigned short h) { return __uint_as_float(((unsigned)h) << 16); }

// ---------------------------------------------------------------------------
// merged cast (5 f32->bf16 segments) + edge_count kernel.
// blocks [0,10176): cast float4/thread; blocks [10176,10688): in-degree count.
// cnt must be zeroed beforehand (hipMemsetAsync, stream-ordered).
// ---------------------------------------------------------------------------
constexpr int CS0 = 1572864;            // x:    M*768/4
constexpr int CS1 = CS0 + 147456;       // gcnW: 768*768/4
constexpr int CS2 = CS1 + 442368;       // ipw:  2304*768/4
constexpr int CS3 = CS2 + 147456;       // opw:  768*768/4
constexpr int CS4 = CS3 + 294912;       // gw:   768*1536/4  (= 2605056)
constexpr int CAST_BLOCKS = CS4 / 256;          // 10176
constexpr int CNT_BLOCKS  = (B * E) / 256;      // 512
__global__ void cast_count_kernel(
    const float* __restrict__ x, const float* __restrict__ gcnW,
    const float* __restrict__ ipw, const float* __restrict__ opw,
    const float* __restrict__ gw,
    unsigned short* __restrict__ xb16, unsigned short* __restrict__ wcat,
    unsigned short* __restrict__ wout, unsigned short* __restrict__ wgate,
    const int* __restrict__ ei, int* __restrict__ cnt) {
  const int blk = blockIdx.x;
  if (blk < CAST_BLOCKS) {
    const int i = blk * 256 + threadIdx.x;
    const float* in; unsigned short* out; int off;
    if (i < CS0)      { in = x;    out = xb16;           off = i; }
    else if (i < CS1) { in = gcnW; out = wcat;           off = i - CS0; }
    else if (i < CS2) { in = ipw;  out = wcat + 589824;  off = i - CS1; }
    else if (i < CS3) { in = opw;  out = wout;           off = i - CS2; }
    else              { in = gw;   out = wgate;          off = i - CS3; }
    float4 v = ((const float4*)in)[off];
    ushort4 o;
    o.x = f2b(v.x); o.y = f2b(v.y); o.z = f2b(v.z); o.w = f2b(v.w);
    ((ushort4*)out)[off] = o;
  } else {
    const int j = (blk - CAST_BLOCKS) * 256 + threadIdx.x;   // < B*E
    const int b = j >> 14, e = j & (E - 1);
    const int dst = ei[(b << 15) + E + e];
    atomicAdd(&cnt[(b << 10) + dst], 1);
  }
}

// per-batch exclusive scan of counts (1024 entries) + dinv = rsqrt(1+cnt)
__global__ __launch_bounds__(1024) void scan_offs_kernel(
    const int* __restrict__ cnt, int* __restrict__ offs,
    int* __restrict__ cursor, float* __restrict__ dinv) {
  __shared__ int buf[1024];
  const int b = blockIdx.x, i = threadIdx.x, g = (b << 10) + i;
  const int c = cnt[g];
  buf[i] = c;
  __syncthreads();
  for (int off = 1; off < 1024; off <<= 1) {
    int t = (i >= off) ? buf[i - off] : 0;
    __syncthreads();
    buf[i] += t;
    __syncthreads();
  }
  const int excl = buf[i] - c;
  offs[g] = excl;
  cursor[g] = excl;
  dinv[g] = rsqrtf((float)(c + 1));           // self-loop included
}

// stores SRC (not edge id) -> agg loop has one fewer dependent load
__global__ void edge_fill_kernel(const int* __restrict__ ei,
                                 int* __restrict__ cursor, int* __restrict__ elist) {
  int i = blockIdx.x * 256 + threadIdx.x;
  int b = i >> 14, e = i & (E - 1);
  int src = ei[(b << 15) + e];
  int dst = ei[(b << 15) + E + e];
  int slot = atomicAdd(&cursor[(b << 10) + dst], 1);
  elist[(b << 14) + slot] = src;
}

// ---------------------------------------------------------------------------
// bf16 MFMA GEMM (R10 structure — proven ceiling for this shape):
// BM=128, BN in {64,128}, BK=32, double-buffered, counted vmcnt,
// conflict-free LDS quad swizzle, XCD-contiguous grid.
// ---------------------------------------------------------------------------
constexpr int EPI_FUSED = 0;  // c<768 -> h bf16 [B,N,D]; else qkv split
constexpr int EPI_ATTN  = 1;  // -> cat bf16 [r, 768+c]
constexpr int EPI_GATE  = 2;  // -> sigmoid -> gate bf16 [r,c]

template <int EPI, int BN, int K, int GX, int GY>
__global__ __launch_bounds__(256) void gemm_bt(
    const unsigned short* __restrict__ A, const unsigned short* __restrict__ W,
    const float* __restrict__ bias,
    void* __restrict__ p0, void* __restrict__ p1, void* __restrict__ p2,
    void* __restrict__ p3) {
  constexpr int NW = BN / 32;          // n-fragments per wave
  constexpr int NT = K / 32;           // K-steps
  __shared__ __align__(16) unsigned short sA[2][128][32];
  __shared__ __align__(16) unsigned short sB[2][BN][32];
  const int tid = threadIdx.x;
  const int lane = tid & 63, wid = tid >> 6;
  const int wm = wid >> 1, wn = wid & 1;
  const int bid = blockIdx.x;
  const int xcd = bid & 7, slot = bid >> 3;
  const int by = xcd * (GY / 8) + slot / GX;
  const int bx = slot % GX;
  const int m0 = by * 128, n0 = bx * BN;
  const int l15 = lane & 15, lhi = lane >> 4;
  const int srow = lane >> 2;
  const int scol = (((lane & 3) ^ ((lane >> 3) & 3))) * 8;  // pre-swizzled src
  const int rcol = ((lhi ^ ((l15 >> 1) & 3))) * 8;          // read-side swizzle

  f32x4 acc[4][NW] = {};

  const unsigned short* pa = A + ((size_t)(m0 + wid * 32 + srow)) * K + scol;
  const unsigned short* pb = W + ((size_t)(n0 + wid * (BN / 4) + srow)) * K + scol;

  auto stage = [&](int buf) {
    GLOAD(pa,          &sA[buf][wid * 32][0]);
    GLOAD(pa + 16 * K, &sA[buf][wid * 32 + 16][0]);
    GLOAD(pb,          &sB[buf][wid * (BN / 4)][0]);
    if constexpr (BN == 128) GLOAD(pb + 16 * K, &sB[buf][wid * 32 + 16][0]);
    pa += 32; pb += 32;
  };

  stage(0);
  int cur = 0;
  for (int kt = 0; kt < NT; ++kt) {
    if (kt + 1 < NT) {
      stage(cur ^ 1);
      if constexpr (BN == 128) asm volatile("s_waitcnt vmcnt(4)" ::: "memory");
      else                     asm volatile("s_waitcnt vmcnt(3)" ::: "memory");
    } else {
      asm volatile("s_waitcnt vmcnt(0)" ::: "memory");
    }
    __builtin_amdgcn_s_barrier();          // all waves' tile-kt loads landed
    __builtin_amdgcn_sched_barrier(0);

    b16x8 af[4], bfr[NW];
#pragma unroll
    for (int i = 0; i < 4; ++i)
      af[i] = *(const b16x8*)&sA[cur][wm * 64 + i * 16 + l15][rcol];
#pragma unroll
    for (int j = 0; j < NW; ++j)
      bfr[j] = *(const b16x8*)&sB[cur][wn * (BN / 2) + j * 16 + l15][rcol];
#pragma unroll
    for (int i = 0; i < 4; ++i)
#pragma unroll
      for (int j = 0; j < NW; ++j)
        acc[i][j] = __builtin_amdgcn_mfma_f32_16x16x32_bf16(af[i], bfr[j], acc[i][j], 0, 0, 0);

    __builtin_amdgcn_sched_barrier(0);     // reads stay above this barrier
    __builtin_amdgcn_s_barrier();          // readers done before buf reuse
    cur ^= 1;
  }

  // epilogue: C/D layout col = lane&15, row = (lane>>4)*4 + reg  [HW-verified]
#pragma unroll
  for (int i = 0; i < 4; ++i) {
#pragma unroll
    for (int j = 0; j < NW; ++j) {
      const int c = n0 + wn * (BN / 2) + j * 16 + l15;
      float bv;
      if constexpr (EPI == EPI_FUSED) bv = (c < 768) ? 0.0f : bias[c - 768];
      else bv = bias[c];
#pragma unroll
      for (int g = 0; g < 4; ++g) {
        const int r = m0 + wm * 64 + i * 16 + lhi * 4 + g;
        float v = acc[i][j][g] + bv;
        if constexpr (EPI == EPI_FUSED) {
          const int n = r >> 3, b = r & 7;
          if (c < 768) {
            ((unsigned short*)p0)[((size_t)((b << 10) + n)) * 768 + c] = f2b(v);
          } else {
            const int cc2 = c - 768;
            const int sec = cc2 / 768, cc = cc2 - sec * 768;
            const int hd = cc / 96, dh = cc - hd * 96;
            unsigned short* dst =
                (sec == 0) ? (unsigned short*)p1
                           : (sec == 1 ? (unsigned short*)p2 : (unsigned short*)p3);
            size_t idx;
            if (sec < 2) idx = ((size_t)((b * 8 + hd) * 1024 + n)) * 96 + dh;  // [B,H,N,DH]
            else         idx = ((size_t)((b * 8 + hd) * 96 + dh)) * 1024 + n;  // V^T
            dst[idx] = f2b(v);
          }
        } else if constexpr (EPI == EPI_ATTN) {
          ((unsigned short*)p0)[(size_t)r * 1536 + 768 + c] = f2b(v);
        } else {  // EPI_GATE -> bf16 gate
          ((unsigned short*)p0)[(size_t)r * 768 + c] =
              f2b(1.0f / (1.0f + __expf(-v)));
        }
      }
    }
  }
}

// ---------------------------------------------------------------------------
// MERGED attention + GCN aggregation (data-independent, complementary pipes;
// m114: MFMA-waves and gather-waves co-schedule ~ max not sum).
// blocks [0,1024): flash attention (XCD-grouped by bid&7, as before).
// blocks [1024,9216): aggregation, batch->XCD mapping b = abid&7 so each
//   batch's 1.5MB h16 slice is resident in ONE XCD's 4MB L2.
// ---------------------------------------------------------------------------
__global__ __launch_bounds__(256) void attn_agg_kernel(
    const unsigned short* __restrict__ qb, const unsigned short* __restrict__ kb,
    const unsigned short* __restrict__ vb, unsigned short* __restrict__ ctx,
    const unsigned short* __restrict__ h16,
    const int* __restrict__ cnt, const int* __restrict__ offs,
    const int* __restrict__ elist, const float* __restrict__ dinv,
    const float* __restrict__ gcn_b, unsigned short* __restrict__ cat16) {
  __shared__ __align__(16) unsigned short sK[64][104];  // [key][dh], pad 96->104
  __shared__ __align__(16) unsigned short sV[96][72];   // [dh][key], pad 64->72
  __shared__ __align__(16) unsigned short sP[4][16][72];

  if (blockIdx.x >= 1024) {
    // ===================== aggregation path =====================
    if (threadIdx.x >= 192) return;     // 192 thr x 4 dims = 768
    const int abid = blockIdx.x - 1024;
    const int b = abid & 7, n = abid >> 3;   // batch -> XCD (bid%8 dispatch)
    const int bn = (b << 10) + n;
    const int d = threadIdx.x * 4;
    const float dn = dinv[bn];
    const size_t hrow = (size_t)bn * 768;
    ushort4 hv = *(const ushort4*)(h16 + hrow + d);
    float a0 = dn * dn * b2f(hv.x), a1 = dn * dn * b2f(hv.y);
    float a2 = dn * dn * b2f(hv.z), a3 = dn * dn * b2f(hv.w);
    const int st = offs[bn], cv = cnt[bn];
    const int* ep = elist + (b << 14) + st;
    int i = 0;
    for (; i + 2 <= cv; i += 2) {       // two independent gathers in flight
      const int s0 = ep[i], s1 = ep[i + 1];
      const float nv0 = dinv[(b << 10) + s0] * dn;
      const float nv1 = dinv[(b << 10) + s1] * dn;
      const ushort4 r0 = *(const ushort4*)(h16 + ((size_t)((b << 10) + s0)) * 768 + d);
      const ushort4 r1 = *(const ushort4*)(h16 + ((size_t)((b << 10) + s1)) * 768 + d);
      a0 += nv0 * b2f(r0.x) + nv1 * b2f(r1.x);
      a1 += nv0 * b2f(r0.y) + nv1 * b2f(r1.y);
      a2 += nv0 * b2f(r0.z) + nv1 * b2f(r1.z);
      a3 += nv0 * b2f(r0.w) + nv1 * b2f(r1.w);
    }
    if (i < cv) {
      const int s0 = ep[i];
      const float nv0 = dinv[(b << 10) + s0] * dn;
      const ushort4 r0 = *(const ushort4*)(h16 + ((size_t)((b << 10) + s0)) * 768 + d);
      a0 += nv0 * b2f(r0.x); a1 += nv0 * b2f(r0.y);
      a2 += nv0 * b2f(r0.z); a3 += nv0 * b2f(r0.w);
    }
    const float4 bb = *(const float4*)(gcn_b + d);
    a0 += bb.x; a1 += bb.y; a2 += bb.z; a3 += bb.w;
    const size_t crow = ((size_t)n * 8 + b) * 1536;
    ushort4 co; co.x = f2b(a0); co.y = f2b(a1); co.z = f2b(a2); co.w = f2b(a3);
    *(ushort4*)(cat16 + crow + d) = co;
    return;
  }

  // ===================== attention path =====================
  const int tid = threadIdx.x, lane = tid & 63, wid = tid >> 6;
  const int l15 = lane & 15, lhi = lane >> 4;
  const int bid = blockIdx.x;
  const int xcd = bid & 7, slot = bid >> 3;
  const int bh = xcd * 8 + (slot >> 4);
  const int q0 = (slot & 15) * 64;
  const float SCL = 0.14724445f;  // (1/sqrt(96)) * log2(e)

  b16x8 qf[3];
  const size_t qbase = ((size_t)bh * 1024 + q0 + wid * 16 + l15) * 96 + lhi * 8;
#pragma unroll
  for (int ks = 0; ks < 3; ++ks) qf[ks] = *(const b16x8*)(qb + qbase + ks * 32);

  const int c0 = tid, c1 = 256 + tid, c2 = 512 + tid;
  const unsigned short* kp0 = kb + ((size_t)bh * 1024 + c0 / 12) * 96 + (c0 % 12) * 8;
  const unsigned short* kp1 = kb + ((size_t)bh * 1024 + c1 / 12) * 96 + (c1 % 12) * 8;
  const unsigned short* kp2 = kb + ((size_t)bh * 1024 + c2 / 12) * 96 + (c2 % 12) * 8;
  const unsigned short* vp0 = vb + ((size_t)bh * 96 + (c0 >> 3)) * 1024 + (c0 & 7) * 8;
  const unsigned short* vp1 = vb + ((size_t)bh * 96 + (c1 >> 3)) * 1024 + (c1 & 7) * 8;
  const unsigned short* vp2 = vb + ((size_t)bh * 96 + (c2 >> 3)) * 1024 + (c2 & 7) * 8;
  unsigned short* sk0 = &sK[c0 / 12][(c0 % 12) * 8];
  unsigned short* sk1 = &sK[c1 / 12][(c1 % 12) * 8];
  unsigned short* sk2 = &sK[c2 / 12][(c2 % 12) * 8];
  unsigned short* sv0 = &sV[c0 >> 3][(c0 & 7) * 8];
  unsigned short* sv1 = &sV[c1 >> 3][(c1 & 7) * 8];
  unsigned short* sv2 = &sV[c2 >> 3][(c2 & 7) * 8];

  uint4 k0 = *(const uint4*)kp0, k1 = *(const uint4*)kp1, k2 = *(const uint4*)kp2;
  uint4 v0 = *(const uint4*)vp0, v1 = *(const uint4*)vp1, v2 = *(const uint4*)vp2;

  f32x4 accO[6] = {};
  float ssum[4] = {0.f, 0.f, 0.f, 0.f};

  for (int kt = 0; kt < 16; ++kt) {
    __syncthreads();
    *(uint4*)sk0 = k0; *(uint4*)sk1 = k1; *(uint4*)sk2 = k2;
    *(uint4*)sv0 = v0; *(uint4*)sv1 = v1; *(uint4*)sv2 = v2;
    __syncthreads();
    if (kt < 15) {
      kp0 += 64 * 96; kp1 += 64 * 96; kp2 += 64 * 96;
      vp0 += 64;      vp1 += 64;      vp2 += 64;
      k0 = *(const uint4*)kp0; k1 = *(const uint4*)kp1; k2 = *(const uint4*)kp2;
      v0 = *(const uint4*)vp0; v1 = *(const uint4*)vp1; v2 = *(const uint4*)vp2;
    }

    f32x4 sf[4] = {};
    __builtin_amdgcn_s_setprio(1);
#pragma unroll
    for (int f = 0; f < 4; ++f) {
#pragma unroll
      for (int ks = 0; ks < 3; ++ks) {
        b16x8 kf = *(const b16x8*)&sK[f * 16 + l15][ks * 32 + lhi * 8];
        sf[f] = __builtin_amdgcn_mfma_f32_16x16x32_bf16(qf[ks], kf, sf[f], 0, 0, 0);
      }
    }
    __builtin_amdgcn_s_setprio(0);

#pragma unroll
    for (int g = 0; g < 4; ++g) {
#pragma unroll
      for (int f = 0; f < 4; ++f) {
        const float pv = exp2f(sf[f][g] * SCL);
        sP[wid][lhi * 4 + g][f * 16 + l15] = f2b(pv);
        ssum[g] += pv;
      }
    }

    __builtin_amdgcn_s_setprio(1);
#pragma unroll
    for (int ks = 0; ks < 2; ++ks) {
      b16x8 pa = *(const b16x8*)&sP[wid][l15][ks * 32 + lhi * 8];
#pragma unroll
      for (int o = 0; o < 6; ++o) {
        b16x8 vf = *(const b16x8*)&sV[o * 16 + l15][ks * 32 + lhi * 8];
        accO[o] = __builtin_amdgcn_mfma_f32_16x16x32_bf16(pa, vf, accO[o], 0, 0, 0);
      }
    }
    __builtin_amdgcn_s_setprio(0);
  }

#pragma unroll
  for (int g = 0; g < 4; ++g) {
#pragma unroll
    for (int msk = 1; msk < 16; msk <<= 1) ssum[g] += __shfl_xor(ssum[g], msk);
  }

  const int b = bh >> 3, hd = bh & 7;
  float rinv[4];
#pragma unroll
  for (int g = 0; g < 4; ++g) rinv[g] = 1.0f / ssum[g];
#pragma unroll
  for (int o = 0; o < 6; ++o)
#pragma unroll
    for (int g = 0; g < 4; ++g) {
      const int qrow = q0 + wid * 16 + lhi * 4 + g;
      ctx[((size_t)qrow * 8 + b) * 768 + hd * 96 + o * 16 + l15] =
          f2b(accO[o][g] * rinv[g]);
    }
}

// ---------------------------------------------------------------------------
// gate-blend + residual + LayerNorm. block (192 thr) per row.
// ---------------------------------------------------------------------------
__global__ __launch_bounds__(192) void ln_fuse_kernel(
    const unsigned short* __restrict__ gate16,
    const unsigned short* __restrict__ cat16,
    const float* __restrict__ x,
    const float* __restrict__ lng, const float* __restrict__ lnb,
    float* __restrict__ out) {
  const int r = blockIdx.x;
  const int t = threadIdx.x, lane = t & 63, wid = t >> 6;   // 3 waves
  const int d = t * 4;
  const size_t xrow = (size_t)r * 768;
  const size_t crow = (size_t)r * 1536;
  const ushort4 gv = *(const ushort4*)(gate16 + xrow + d);
  const ushort4 cv = *(const ushort4*)(cat16 + crow + d);        // gcn
  const ushort4 av = *(const ushort4*)(cat16 + crow + 768 + d);  // attn
  const float4 xv = *(const float4*)(x + xrow + d);
  const float g0 = b2f(gv.x), g1 = b2f(gv.y), g2 = b2f(gv.z), g3 = b2f(gv.w);
  float f0 = g0 * b2f(cv.x) + (1.f - g0) * b2f(av.x) + xv.x;
  float f1 = g1 * b2f(cv.y) + (1.f - g1) * b2f(av.y) + xv.y;
  float f2 = g2 * b2f(cv.z) + (1.f - g2) * b2f(av.z) + xv.z;
  float f3 = g3 * b2f(cv.w) + (1.f - g3) * b2f(av.w) + xv.w;
  float s1 = f0 + f1 + f2 + f3;
  float s2 = f0 * f0 + f1 * f1 + f2 * f2 + f3 * f3;
#pragma unroll
  for (int msk = 1; msk < 64; msk <<= 1) {
    s1 += __shfl_xor(s1, msk);
    s2 += __shfl_xor(s2, msk);
  }
  __shared__ float p1[3], p2[3];
  if (lane == 0) { p1[wid] = s1; p2[wid] = s2; }
  __syncthreads();
  s1 = p1[0] + p1[1] + p1[2];
  s2 = p2[0] + p2[1] + p2[2];
  const float mu = s1 * (1.f / 768.f);
  float var = s2 * (1.f / 768.f) - mu * mu;
  var = fmaxf(var, 0.f);
  const float rstd = rsqrtf(var + LN_EPS);
  const float4 lg = *(const float4*)(lng + d);
  const float4 lb = *(const float4*)(lnb + d);
  float4 o;
  o.x = (f0 - mu) * rstd * lg.x + lb.x;
  o.y = (f1 - mu) * rstd * lg.y + lb.y;
  o.z = (f2 - mu) * rstd * lg.z + lb.z;
  o.w = (f3 - mu) * rstd * lg.w + lb.w;
  *(float4*)(out + xrow + d) = o;
}

// ---------------------------------------------------------------------------
extern "C" void kernel_launch(void* const* d_in, const int* in_sizes, int n_in,
                              void* d_out, int out_size, void* d_ws, size_t ws_size,
                              hipStream_t stream) {
  const float* x     = (const float*)d_in[0];
  const int*   ei    = (const int*)d_in[1];
  const float* gcnW  = (const float*)d_in[2];
  const float* gcnb  = (const float*)d_in[3];
  const float* ipw   = (const float*)d_in[4];
  const float* ipb   = (const float*)d_in[5];
  const float* opw   = (const float*)d_in[6];
  const float* opb   = (const float*)d_in[7];
  const float* gw    = (const float*)d_in[8];
  const float* gb    = (const float*)d_in[9];
  const float* lng   = (const float*)d_in[10];
  const float* lnb   = (const float*)d_in[11];
  float* out = (float*)d_out;

  char* p = (char*)d_ws;
  auto alloc = [&](size_t bytes) { void* q = p; p += (bytes + 255) & ~(size_t)255; return q; };

  unsigned short* xb16  = (unsigned short*)alloc((size_t)M * 768 * 2);   // also ctx16
  unsigned short* wcat  = (unsigned short*)alloc((size_t)3072 * 768 * 2); // [wgcn;wqkv]
  unsigned short* wout  = (unsigned short*)alloc((size_t)768 * 768 * 2);
  unsigned short* wgate = (unsigned short*)alloc((size_t)768 * 1536 * 2);
  unsigned short* qb    = (unsigned short*)alloc((size_t)B * H * N * DH * 2); // also gate16
  unsigned short* kb    = (unsigned short*)alloc((size_t)B * H * N * DH * 2);
  unsigned short* vb    = (unsigned short*)alloc((size_t)B * H * DH * N * 2);
  unsigned short* h16   = (unsigned short*)alloc((size_t)M * 768 * 2);
  unsigned short* cat16 = (unsigned short*)alloc((size_t)M * 1536 * 2);
  int* cnt    = (int*)alloc(8192 * 4);
  int* offs   = (int*)alloc(8192 * 4);
  int* cursor = (int*)alloc(8192 * 4);
  float* dinv = (float*)alloc(8192 * 4);
  int* elist  = (int*)alloc((size_t)B * E * 4);

  // safe aliases (serial-stream ordering makes these race-free):
  unsigned short* ctx16  = xb16;  // written by attn AFTER last read of xb16 (fused gemm)
  unsigned short* gate16 = qb;    // written by gate gemm AFTER attn reads qb

  // 1) zero degree counters (stream-ordered), then casts + edge_count
  hipMemsetAsync(cnt, 0, 8192 * 4, stream);
  cast_count_kernel<<<CAST_BLOCKS + CNT_BLOCKS, 256, 0, stream>>>(
      x, gcnW, ipw, opw, gw, xb16, wcat, wout, wgate, ei, cnt);

  // 2) CSR: scan + fill (separate, fully-parallel fill)
  scan_offs_kernel<<<8, 1024, 0, stream>>>(cnt, offs, cursor, dinv);
  edge_fill_kernel<<<(B * E) / 256, 256, 0, stream>>>(ei, cursor, elist);

  // 3) fused GCN-linear + QKV GEMM; merged attn+agg; out-proj; gate
  gemm_bt<EPI_FUSED, 128, 768, 24, 64><<<1536, 256, 0, stream>>>(
      xb16, wcat, ipb, (void*)h16, (void*)qb, (void*)kb, (void*)vb);
  attn_agg_kernel<<<1024 + 8192, 256, 0, stream>>>(
      qb, kb, vb, ctx16, h16, cnt, offs, elist, dinv, gcnb, cat16);
  gemm_bt<EPI_ATTN, 64, 768, 12, 64><<<768, 256, 0, stream>>>(
      ctx16, wout, opb, (void*)cat16, nullptr, nullptr, nullptr);
  gemm_bt<EPI_GATE, 64, 1536, 12, 64><<<768, 256, 0, stream>>>(
      cat16, wgate, gb, (void*)gate16, nullptr, nullptr, nullptr);

  // 4) gate blend + residual + LayerNorm
  ln_fuse_kernel<<<8192, 192, 0, stream>>>(gate16, cat16, x, lng, lnb, out);
}